// Round 14
// baseline (6905.324 us; speedup 1.0000x reference)
//
#include <hip/hip_runtime.h>

typedef __attribute__((ext_vector_type(4))) float  f32x4;
typedef __attribute__((ext_vector_type(8))) short  bf16x8;

__device__ __forceinline__ short f2bf(float f) {
    unsigned u = __builtin_bit_cast(unsigned, f);
    unsigned r = (u + 0x7FFFu + ((u >> 16) & 1u)) >> 16;
    return (short)r;
}

// ============ unified f64 GEMM: f64 LDS, 8x4 micro, BIT-EXACT k-sequential chain ============
// B always [K][ldb] row-major. P2==nullptr: C = relu(fl32(acc)+P1[col]) (encoder).
// P2!=nullptr: d2 = fl(fl(P1[row] - fl(2*fl32(acc))) + P2[col]).
// Ws layout (68-double rows), 16B-slot swizzle for quad q=tx:
//   col0(q) = 4q + 2*(q>>3), col1(q) = 4q + 2 - 2*(q>>3)  — injective, 2-way banks (free).
// launch_bounds (256,6): 6 blocks/CU (LDS 24.6KB x6 = 147KB <= 160KB; VGPR 48 <= 85).
__global__ __launch_bounds__(256, 6)
void gemm_f64(const float* __restrict__ A, const float* __restrict__ B,
              const float* __restrict__ P1, const float* __restrict__ P2,
              float* __restrict__ C, int lda, int ldb, int ldc, int K)
{
    __shared__ double As[16][128];   // k-major
    __shared__ double Ws[16][68];    // k-major, slot-swizzled
    const int tid = threadIdx.x;
    const size_t bm = (size_t)blockIdx.x * 128;
    const size_t bn = (size_t)blockIdx.y * 64;
    const int ty = tid >> 4, tx = tid & 15;

    double acc[8][4];
#pragma unroll
    for (int i = 0; i < 8; ++i)
#pragma unroll
        for (int j = 0; j < 4; ++j) acc[i][j] = 0.0;

    const int ar = tid >> 1, ak = (tid & 1) * 8;        // A staging: row, k-chunk
    const int wr = tid >> 4;                            // B staging: k-row
    const int wq = tx * 4;                              // logical col base
    const int qh = tx >> 3;
    const int col0 = wq + 2 * qh;                       // phys col of logical 4tx..4tx+1
    const int col1 = wq + 2 - 2 * qh;                   // phys col of logical 4tx+2..4tx+3

    for (int k0 = 0; k0 < K; k0 += 16) {
        const float* ap = A + (bm + ar) * (size_t)lda + k0 + ak;
        float4 av0 = *(const float4*)(ap);
        float4 av1 = *(const float4*)(ap + 4);
        float4 wv  = *(const float4*)(B + (size_t)(k0 + wr) * ldb + bn + wq);
        __syncthreads();
        As[ak + 0][ar] = (double)av0.x;  As[ak + 1][ar] = (double)av0.y;
        As[ak + 2][ar] = (double)av0.z;  As[ak + 3][ar] = (double)av0.w;
        As[ak + 4][ar] = (double)av1.x;  As[ak + 5][ar] = (double)av1.y;
        As[ak + 6][ar] = (double)av1.z;  As[ak + 7][ar] = (double)av1.w;
        *(double2*)&Ws[wr][col0] = make_double2((double)wv.x, (double)wv.y);
        *(double2*)&Ws[wr][col1] = make_double2((double)wv.z, (double)wv.w);
        __syncthreads();
#pragma unroll
        for (int kk = 0; kk < 16; ++kk) {
            const double* arp = &As[kk][ty * 8];
            double a[8];
#pragma unroll
            for (int t = 0; t < 8; ++t) a[t] = arp[t];
            double2 b01 = *(const double2*)&Ws[kk][col0];
            double2 b23 = *(const double2*)&Ws[kk][col1];
            double b[4] = {b01.x, b01.y, b23.x, b23.y};
#pragma unroll
            for (int i = 0; i < 8; ++i)
#pragma unroll
                for (int j = 0; j < 4; ++j)
                    acc[i][j] = fma(a[i], b[j], acc[i][j]);
        }
    }
#pragma unroll
    for (int i = 0; i < 8; ++i) {
        const size_t row = bm + ty * 8 + i;
        float o[4];
        if (P2 == nullptr) {   // encoder epilogue (bit-exact round-5 rounding points)
#pragma unroll
            for (int j = 0; j < 4; ++j) {
                float mm = (float)acc[i][j];
                float v  = __fadd_rn(mm, P1[bn + tx * 4 + j]);
                o[j] = fmaxf(v, 0.f);
            }
        } else {               // d2 epilogue
            const float z2 = P1[row];
#pragma unroll
            for (int j = 0; j < 4; ++j) {
                float m32  = (float)acc[i][j];
                float twom = __fmul_rn(2.0f, m32);
                float t    = __fsub_rn(z2, twom);
                o[j] = __fadd_rn(t, P2[bn + tx * 4 + j]);
            }
        }
        *(float4*)(C + row * (size_t)ldc + bn + tx * 4) = make_float4(o[0], o[1], o[2], o[3]);
    }
}

// ---------- E transpose: [256][512] -> Et [512][256] (exact f32 copy) ----------
__global__ __launch_bounds__(256)
void transpose_f32(const float* __restrict__ in, float* __restrict__ out)
{
    int i = blockIdx.x * 256 + threadIdx.x;   // i = k*256 + r
    int r = i & 255, k = i >> 8;
    out[i] = in[r * 512 + k];
}

// ---------- numpy-pairwise f32 row sum-of-squares, n=512 (bit-exact) ----------
__device__ __forceinline__ float np_pairwise_sq_512(const float* __restrict__ p)
{
    float b[4];
#pragma unroll
    for (int blk = 0; blk < 4; ++blk) {
        const float* q = p + blk * 128;
        float r[8];
#pragma unroll
        for (int j = 0; j < 8; ++j) { float v = q[j]; r[j] = __fmul_rn(v, v); }
        for (int t = 1; t < 16; ++t)
#pragma unroll
            for (int j = 0; j < 8; ++j) {
                float v = q[8 * t + j];
                r[j] = __fadd_rn(r[j], __fmul_rn(v, v));
            }
        float s01 = __fadd_rn(r[0], r[1]), s23 = __fadd_rn(r[2], r[3]);
        float s45 = __fadd_rn(r[4], r[5]), s67 = __fadd_rn(r[6], r[7]);
        b[blk] = __fadd_rn(__fadd_rn(s01, s23), __fadd_rn(s45, s67));
    }
    return __fadd_rn(__fadd_rn(b[0], b[1]), __fadd_rn(b[2], b[3]));
}

__global__ __launch_bounds__(256)
void rowsq_np(const float* __restrict__ a, float* __restrict__ out, int nrows)
{
    int r = blockIdx.x * 256 + threadIdx.x;
    if (r >= nrows) return;
    out[r] = np_pairwise_sq_512(a + (size_t)r * 512);
}

// ---------- argmin (f32, first-index ties) + gather (f32 + bf16) ----------
__global__ __launch_bounds__(256)
void argmin_gather(const float* __restrict__ scores, const float* __restrict__ E,
                   float* __restrict__ q, short* __restrict__ qb)
{
    const int wave = threadIdx.x >> 6;
    const int lane = threadIdx.x & 63;
    const size_t row = (size_t)blockIdx.x * 4 + wave;
    const float* srow = scores + row * 256;
    float bv = srow[lane];
    int bi = lane;
#pragma unroll
    for (int t = 1; t < 4; ++t) {
        int i = lane + t * 64;
        float v = srow[i];
        if (v < bv) { bv = v; bi = i; }
    }
#pragma unroll
    for (int m = 32; m; m >>= 1) {
        float ov = __shfl_xor(bv, m);
        int oi = __shfl_xor(bi, m);
        if (ov < bv || (ov == bv && oi < bi)) { bv = ov; bi = oi; }
    }
    const float4* er = (const float4*)(E + (size_t)bi * 512);
    float4 e0 = er[lane * 2], e1 = er[lane * 2 + 1];
    float4* qr = (float4*)(q + row * 512);
    qr[lane * 2]     = e0;
    qr[lane * 2 + 1] = e1;
    bf16x8 bv8;
    bv8[0] = f2bf(e0.x); bv8[1] = f2bf(e0.y); bv8[2] = f2bf(e0.z); bv8[3] = f2bf(e0.w);
    bv8[4] = f2bf(e1.x); bv8[5] = f2bf(e1.y); bv8[6] = f2bf(e1.z); bv8[7] = f2bf(e1.w);
    *(bf16x8*)&qb[row * 512 + lane * 8] = bv8;
}

// ---------- loss ----------
__global__ __launch_bounds__(256)
void loss_partial(const float* __restrict__ z, const float* __restrict__ q,
                  double* __restrict__ partials, long n4)
{
    const float4* z4 = (const float4*)z;
    const float4* q4 = (const float4*)q;
    double s = 0.0;
    for (long i = (long)blockIdx.x * 256 + threadIdx.x; i < n4; i += (long)gridDim.x * 256) {
        float4 a = z4[i], b = q4[i];
        double dx = (double)a.x - b.x, dy = (double)a.y - b.y;
        double dz = (double)a.z - b.z, dw = (double)a.w - b.w;
        s += dx * dx + dy * dy + dz * dz + dw * dw;
    }
    __shared__ double red[256];
    red[threadIdx.x] = s;
    __syncthreads();
    for (int off = 128; off; off >>= 1) {
        if (threadIdx.x < off) red[threadIdx.x] += red[threadIdx.x + off];
        __syncthreads();
    }
    if (threadIdx.x == 0) partials[blockIdx.x] = red[0];
}

__global__ __launch_bounds__(256)
void loss_final(const double* __restrict__ partials, float* __restrict__ out)
{
    __shared__ double red[256];
    double s = 0.0;
    for (int i = threadIdx.x; i < 1024; i += 256) s += partials[i];
    red[threadIdx.x] = s;
    __syncthreads();
    for (int off = 128; off; off >>= 1) {
        if (threadIdx.x < off) red[threadIdx.x] += red[threadIdx.x + off];
        __syncthreads();
    }
    if (threadIdx.x == 0) out[0] = (float)(red[0] * (1.25 / 16777216.0));
}

// ---------- transpose f32 [K][N] -> bf16 [N][K] ----------
__global__ __launch_bounds__(256)
void transpose_bf16(const float* __restrict__ in, short* __restrict__ out,
                    int N, int kshift, long total)
{
    long i = (long)blockIdx.x * 256 + threadIdx.x;
    if (i >= total) return;
    int k = (int)(i & ((1 << kshift) - 1));
    int n = (int)(i >> kshift);
    out[i] = f2bf(in[(size_t)k * N + n]);
}

// ---------- decoder GEMM via bf16 MFMA — unchanged (round 8 proven) ----------
template<bool RELU, bool OUTBF16>
__global__ __launch_bounds__(256)
void gemm_dec_bf16(const short* __restrict__ A, const short* __restrict__ Bt,
                   const float* __restrict__ bias, void* __restrict__ Cout,
                   int N, int K)
{
    __shared__ short As[128][72];
    __shared__ short Bs[128][72];
    const int tid = threadIdx.x;
    const int lane = tid & 63;
    const int wave = tid >> 6;
    const int wm = (wave >> 1) * 64;
    const int wn = (wave & 1) * 64;
    const size_t bm = (size_t)blockIdx.x * 128;
    const size_t bn = (size_t)blockIdx.y * 128;
    const int fr = lane & 15;
    const int fk8 = (lane >> 4) * 8;

    f32x4 acc[4][4];
#pragma unroll
    for (int m = 0; m < 4; ++m)
#pragma unroll
        for (int n = 0; n < 4; ++n) acc[m][n] = (f32x4)0.f;

    const int sr = tid >> 1;
    const int sk = (tid & 1) * 32;

    for (int k0 = 0; k0 < K; k0 += 64) {
        const uint4* ap4 = (const uint4*)(A + (bm + sr) * (size_t)K + k0 + sk);
        const uint4* bp4 = (const uint4*)(Bt + (bn + sr) * (size_t)K + k0 + sk);
        uint4 av[4], bv[4];
#pragma unroll
        for (int j = 0; j < 4; ++j) { av[j] = ap4[j]; bv[j] = bp4[j]; }
        __syncthreads();
#pragma unroll
        for (int j = 0; j < 4; ++j) {
            *(uint4*)&As[sr][sk + 8 * j] = av[j];
            *(uint4*)&Bs[sr][sk + 8 * j] = bv[j];
        }
        __syncthreads();
#pragma unroll
        for (int kk = 0; kk < 2; ++kk) {
            bf16x8 a[4], b[4];
#pragma unroll
            for (int m = 0; m < 4; ++m)
                a[m] = *(const bf16x8*)&As[wm + m * 16 + fr][kk * 32 + fk8];
#pragma unroll
            for (int n = 0; n < 4; ++n)
                b[n] = *(const bf16x8*)&Bs[wn + n * 16 + fr][kk * 32 + fk8];
#pragma unroll
            for (int m = 0; m < 4; ++m)
#pragma unroll
                for (int n = 0; n < 4; ++n)
                    acc[m][n] = __builtin_amdgcn_mfma_f32_16x16x32_bf16(a[m], b[n], acc[m][n], 0, 0, 0);
        }
    }
#pragma unroll
    for (int m = 0; m < 4; ++m)
#pragma unroll
        for (int n = 0; n < 4; ++n)
#pragma unroll
            for (int i = 0; i < 4; ++i) {
                const size_t row = bm + wm + m * 16 + (lane >> 4) * 4 + i;
                const int col = (int)bn + wn + n * 16 + fr;
                float v = acc[m][n][i] + bias[col];
                if (RELU) v = fmaxf(v, 0.f);
                if (OUTBF16) ((short*)Cout)[row * (size_t)N + col] = f2bf(v);
                else         ((float*)Cout)[row * (size_t)N + col] = v;
            }
}

extern "C" void kernel_launch(void* const* d_in, const int* in_sizes, int n_in,
                              void* d_out, int out_size, void* d_ws, size_t ws_size,
                              hipStream_t stream)
{
    const float* x   = (const float*)d_in[0];
    const float* W1  = (const float*)d_in[1];
    const float* b1  = (const float*)d_in[2];
    const float* W2  = (const float*)d_in[3];
    const float* b2  = (const float*)d_in[4];
    const float* E   = (const float*)d_in[5];
    const float* Wd1 = (const float*)d_in[6];
    const float* bd1 = (const float*)d_in[7];
    const float* Wd2 = (const float*)d_in[8];
    const float* bd2 = (const float*)d_in[9];
    float* out = (float*)d_out;

    float* ws = (float*)d_ws;
    float*  h    = ws;                          // f32 [0, 33.5M); dead after GEMM2
    short*  a1b  = (short*)ws;                  // bf16 overlay on dead h
    short*  qb   = (short*)(ws + 16777216);
    float*  z    = ws + 33554432;               // 16,777,216 f32
    float*  q    = ws + 50331648;               // 16,777,216 f32
    float*  d2   = ws + 67108864;               //  8,388,608 f32; dead after argmin
    short*  Wd1t = (short*)(ws + 67108864);     // overlay on dead d2
    short*  Wd2t = (short*)(ws + 67108864 + 65536);
    float*  z2v  = ws + 75497472;               // 32,768
    float*  e2v  = ws + 75530240;               // 256
    double* partials = (double*)(ws + 75530496);// 1024 f64 = 2048 f32 slots
    float*  Et   = ws + 75532544;               // 512*256 = 131,072 f32

    dim3 blk(256);
    // encoder: f64-LDS injective swizzle, 6 blocks/CU, bit-exact chain (round-5/8 values)
    gemm_f64<<<dim3(512, 8), blk, 0, stream>>>(x, W1, b1, nullptr, h, 1024, 512, 512, 1024);
    gemm_f64<<<dim3(512, 4), blk, 0, stream>>>(h, W2, b2, nullptr, z, 512, 256, 256, 512);
    // VQ (bit-exact round-5 semantics); E transposed exactly so d2 reuses the same kernel
    transpose_f32<<<dim3(512), blk, 0, stream>>>(E, Et);
    rowsq_np<<<dim3(1), blk, 0, stream>>>(E, e2v, 256);
    rowsq_np<<<dim3(128), blk, 0, stream>>>(z, z2v, 32768);
    gemm_f64<<<dim3(256, 4), blk, 0, stream>>>(z, Et, z2v, e2v, d2, 512, 256, 256, 512);
    argmin_gather<<<dim3(8192), blk, 0, stream>>>(d2, E, q, qb);
    // vq_loss = 1.25 * mean((q - z)^2)
    loss_partial<<<dim3(1024), blk, 0, stream>>>(z, q, partials, 4194304L);
    loss_final<<<dim3(1), blk, 0, stream>>>(partials, out + (size_t)out_size - 1);
    // decoder weights -> bf16 [N][K] (d2 dead)
    transpose_bf16<<<dim3(512), blk, 0, stream>>>(Wd1, Wd1t, 512, 8, 131072L);
    transpose_bf16<<<dim3(2048), blk, 0, stream>>>(Wd2, Wd2t, 1024, 9, 524288L);
    // decoder (bf16 MFMA; zq == q in forward)
    gemm_dec_bf16<true,  true ><<<dim3(512, 4), blk, 0, stream>>>(qb,  Wd1t, bd1, a1b, 512, 256);
    gemm_dec_bf16<false, false><<<dim3(512, 8), blk, 0, stream>>>(a1b, Wd2t, bd2, out, 1024, 512);
}

// Round 15
// 2379.322 us; speedup vs baseline: 2.9022x; 2.9022x over previous
//
#include <hip/hip_runtime.h>

typedef __attribute__((ext_vector_type(4))) float  f32x4;
typedef __attribute__((ext_vector_type(8))) short  bf16x8;

__device__ __forceinline__ short f2bf(float f) {
    unsigned u = __builtin_bit_cast(unsigned, f);
    unsigned r = (u + 0x7FFFu + ((u >> 16) & 1u)) >> 16;
    return (short)r;
}

// ============ unified f64 GEMM: f64 LDS, 8x4 micro, BIT-EXACT k-sequential chain ============
// B always [K][ldb] row-major. P2==nullptr: C = relu(fl32(acc)+P1[col]) (encoder).
// P2!=nullptr: d2 = fl(fl(P1[row] - fl(2*fl32(acc))) + P2[col]).
// Ws layout (68-double rows), 16B-slot swizzle for quad q=tx:
//   col0(q) = 4q + 2*(q>>3), col1(q) = 4q + 2 - 2*(q>>3)  — injective, 2-way banks (free).
// launch_bounds (256,4): proven r13 config. DO NOT raise (r14: (256,6) => compiler
// spilled acc to scratch: VGPR 40, WRITE_SIZE x64, 3.6x slowdown).
// Global loads for tile k0+16 are issued BEFORE the compute phase of tile k0
// (software prefetch) — pure scheduling, bit-identical values.
__global__ __launch_bounds__(256, 4)
void gemm_f64(const float* __restrict__ A, const float* __restrict__ B,
              const float* __restrict__ P1, const float* __restrict__ P2,
              float* __restrict__ C, int lda, int ldb, int ldc, int K)
{
    __shared__ double As[16][128];   // k-major
    __shared__ double Ws[16][68];    // k-major, slot-swizzled
    const int tid = threadIdx.x;
    const size_t bm = (size_t)blockIdx.x * 128;
    const size_t bn = (size_t)blockIdx.y * 64;
    const int ty = tid >> 4, tx = tid & 15;

    double acc[8][4];
#pragma unroll
    for (int i = 0; i < 8; ++i)
#pragma unroll
        for (int j = 0; j < 4; ++j) acc[i][j] = 0.0;

    const int ar = tid >> 1, ak = (tid & 1) * 8;        // A staging: row, k-chunk
    const int wr = tid >> 4;                            // B staging: k-row
    const int wq = tx * 4;                              // logical col base
    const int qh = tx >> 3;
    const int col0 = wq + 2 * qh;                       // phys col of logical 4tx..4tx+1
    const int col1 = wq + 2 - 2 * qh;                   // phys col of logical 4tx+2..4tx+3

    const float* apBase = A + (bm + ar) * (size_t)lda + ak;
    const float* wpBase = B + (size_t)wr * ldb + bn + wq;

    float4 av0 = *(const float4*)(apBase);
    float4 av1 = *(const float4*)(apBase + 4);
    float4 wv  = *(const float4*)(wpBase);

    for (int k0 = 0; k0 < K; k0 += 16) {
        __syncthreads();   // previous iteration's LDS reads complete
        As[ak + 0][ar] = (double)av0.x;  As[ak + 1][ar] = (double)av0.y;
        As[ak + 2][ar] = (double)av0.z;  As[ak + 3][ar] = (double)av0.w;
        As[ak + 4][ar] = (double)av1.x;  As[ak + 5][ar] = (double)av1.y;
        As[ak + 6][ar] = (double)av1.z;  As[ak + 7][ar] = (double)av1.w;
        *(double2*)&Ws[wr][col0] = make_double2((double)wv.x, (double)wv.y);
        *(double2*)&Ws[wr][col1] = make_double2((double)wv.z, (double)wv.w);
        __syncthreads();
        if (k0 + 16 < K) {   // prefetch next tile; latency hides under compute below
            av0 = *(const float4*)(apBase + k0 + 16);
            av1 = *(const float4*)(apBase + k0 + 20);
            wv  = *(const float4*)(wpBase + (size_t)(k0 + 16) * ldb);
        }
#pragma unroll
        for (int kk = 0; kk < 16; ++kk) {
            const double* arp = &As[kk][ty * 8];
            double a[8];
#pragma unroll
            for (int t = 0; t < 8; ++t) a[t] = arp[t];
            double2 b01 = *(const double2*)&Ws[kk][col0];
            double2 b23 = *(const double2*)&Ws[kk][col1];
            double b[4] = {b01.x, b01.y, b23.x, b23.y};
#pragma unroll
            for (int i = 0; i < 8; ++i)
#pragma unroll
                for (int j = 0; j < 4; ++j)
                    acc[i][j] = fma(a[i], b[j], acc[i][j]);
        }
    }
#pragma unroll
    for (int i = 0; i < 8; ++i) {
        const size_t row = bm + ty * 8 + i;
        float o[4];
        if (P2 == nullptr) {   // encoder epilogue (bit-exact round-5 rounding points)
#pragma unroll
            for (int j = 0; j < 4; ++j) {
                float mm = (float)acc[i][j];
                float v  = __fadd_rn(mm, P1[bn + tx * 4 + j]);
                o[j] = fmaxf(v, 0.f);
            }
        } else {               // d2 epilogue
            const float z2 = P1[row];
#pragma unroll
            for (int j = 0; j < 4; ++j) {
                float m32  = (float)acc[i][j];
                float twom = __fmul_rn(2.0f, m32);
                float t    = __fsub_rn(z2, twom);
                o[j] = __fadd_rn(t, P2[bn + tx * 4 + j]);
            }
        }
        *(float4*)(C + row * (size_t)ldc + bn + tx * 4) = make_float4(o[0], o[1], o[2], o[3]);
    }
}

// ---------- E transpose: [256][512] -> Et [512][256] (exact f32 copy) ----------
__global__ __launch_bounds__(256)
void transpose_f32(const float* __restrict__ in, float* __restrict__ out)
{
    int i = blockIdx.x * 256 + threadIdx.x;   // i = k*256 + r
    int r = i & 255, k = i >> 8;
    out[i] = in[r * 512 + k];
}

// ---------- numpy-pairwise f32 row sum-of-squares, n=512 (bit-exact) ----------
__device__ __forceinline__ float np_pairwise_sq_512(const float* __restrict__ p)
{
    float b[4];
#pragma unroll
    for (int blk = 0; blk < 4; ++blk) {
        const float* q = p + blk * 128;
        float r[8];
#pragma unroll
        for (int j = 0; j < 8; ++j) { float v = q[j]; r[j] = __fmul_rn(v, v); }
        for (int t = 1; t < 16; ++t)
#pragma unroll
            for (int j = 0; j < 8; ++j) {
                float v = q[8 * t + j];
                r[j] = __fadd_rn(r[j], __fmul_rn(v, v));
            }
        float s01 = __fadd_rn(r[0], r[1]), s23 = __fadd_rn(r[2], r[3]);
        float s45 = __fadd_rn(r[4], r[5]), s67 = __fadd_rn(r[6], r[7]);
        b[blk] = __fadd_rn(__fadd_rn(s01, s23), __fadd_rn(s45, s67));
    }
    return __fadd_rn(__fadd_rn(b[0], b[1]), __fadd_rn(b[2], b[3]));
}

__global__ __launch_bounds__(256)
void rowsq_np(const float* __restrict__ a, float* __restrict__ out, int nrows)
{
    int r = blockIdx.x * 256 + threadIdx.x;
    if (r >= nrows) return;
    out[r] = np_pairwise_sq_512(a + (size_t)r * 512);
}

// ---------- argmin (f32, first-index ties) + gather (f32 + bf16) ----------
__global__ __launch_bounds__(256)
void argmin_gather(const float* __restrict__ scores, const float* __restrict__ E,
                   float* __restrict__ q, short* __restrict__ qb)
{
    const int wave = threadIdx.x >> 6;
    const int lane = threadIdx.x & 63;
    const size_t row = (size_t)blockIdx.x * 4 + wave;
    const float* srow = scores + row * 256;
    float bv = srow[lane];
    int bi = lane;
#pragma unroll
    for (int t = 1; t < 4; ++t) {
        int i = lane + t * 64;
        float v = srow[i];
        if (v < bv) { bv = v; bi = i; }
    }
#pragma unroll
    for (int m = 32; m; m >>= 1) {
        float ov = __shfl_xor(bv, m);
        int oi = __shfl_xor(bi, m);
        if (ov < bv || (ov == bv && oi < bi)) { bv = ov; bi = oi; }
    }
    const float4* er = (const float4*)(E + (size_t)bi * 512);
    float4 e0 = er[lane * 2], e1 = er[lane * 2 + 1];
    float4* qr = (float4*)(q + row * 512);
    qr[lane * 2]     = e0;
    qr[lane * 2 + 1] = e1;
    bf16x8 bv8;
    bv8[0] = f2bf(e0.x); bv8[1] = f2bf(e0.y); bv8[2] = f2bf(e0.z); bv8[3] = f2bf(e0.w);
    bv8[4] = f2bf(e1.x); bv8[5] = f2bf(e1.y); bv8[6] = f2bf(e1.z); bv8[7] = f2bf(e1.w);
    *(bf16x8*)&qb[row * 512 + lane * 8] = bv8;
}

// ---------- loss ----------
__global__ __launch_bounds__(256)
void loss_partial(const float* __restrict__ z, const float* __restrict__ q,
                  double* __restrict__ partials, long n4)
{
    const float4* z4 = (const float4*)z;
    const float4* q4 = (const float4*)q;
    double s = 0.0;
    for (long i = (long)blockIdx.x * 256 + threadIdx.x; i < n4; i += (long)gridDim.x * 256) {
        float4 a = z4[i], b = q4[i];
        double dx = (double)a.x - b.x, dy = (double)a.y - b.y;
        double dz = (double)a.z - b.z, dw = (double)a.w - b.w;
        s += dx * dx + dy * dy + dz * dz + dw * dw;
    }
    __shared__ double red[256];
    red[threadIdx.x] = s;
    __syncthreads();
    for (int off = 128; off; off >>= 1) {
        if (threadIdx.x < off) red[threadIdx.x] += red[threadIdx.x + off];
        __syncthreads();
    }
    if (threadIdx.x == 0) partials[blockIdx.x] = red[0];
}

__global__ __launch_bounds__(256)
void loss_final(const double* __restrict__ partials, float* __restrict__ out)
{
    __shared__ double red[256];
    double s = 0.0;
    for (int i = threadIdx.x; i < 1024; i += 256) s += partials[i];
    red[threadIdx.x] = s;
    __syncthreads();
    for (int off = 128; off; off >>= 1) {
        if (threadIdx.x < off) red[threadIdx.x] += red[threadIdx.x + off];
        __syncthreads();
    }
    if (threadIdx.x == 0) out[0] = (float)(red[0] * (1.25 / 16777216.0));
}

// ---------- transpose f32 [K][N] -> bf16 [N][K] ----------
__global__ __launch_bounds__(256)
void transpose_bf16(const float* __restrict__ in, short* __restrict__ out,
                    int N, int kshift, long total)
{
    long i = (long)blockIdx.x * 256 + threadIdx.x;
    if (i >= total) return;
    int k = (int)(i & ((1 << kshift) - 1));
    int n = (int)(i >> kshift);
    out[i] = f2bf(in[(size_t)k * N + n]);
}

// ---------- decoder GEMM via bf16 MFMA — unchanged (round 8 proven) ----------
template<bool RELU, bool OUTBF16>
__global__ __launch_bounds__(256)
void gemm_dec_bf16(const short* __restrict__ A, const short* __restrict__ Bt,
                   const float* __restrict__ bias, void* __restrict__ Cout,
                   int N, int K)
{
    __shared__ short As[128][72];
    __shared__ short Bs[128][72];
    const int tid = threadIdx.x;
    const int lane = tid & 63;
    const int wave = tid >> 6;
    const int wm = (wave >> 1) * 64;
    const int wn = (wave & 1) * 64;
    const size_t bm = (size_t)blockIdx.x * 128;
    const size_t bn = (size_t)blockIdx.y * 128;
    const int fr = lane & 15;
    const int fk8 = (lane >> 4) * 8;

    f32x4 acc[4][4];
#pragma unroll
    for (int m = 0; m < 4; ++m)
#pragma unroll
        for (int n = 0; n < 4; ++n) acc[m][n] = (f32x4)0.f;

    const int sr = tid >> 1;
    const int sk = (tid & 1) * 32;

    for (int k0 = 0; k0 < K; k0 += 64) {
        const uint4* ap4 = (const uint4*)(A + (bm + sr) * (size_t)K + k0 + sk);
        const uint4* bp4 = (const uint4*)(Bt + (bn + sr) * (size_t)K + k0 + sk);
        uint4 av[4], bv[4];
#pragma unroll
        for (int j = 0; j < 4; ++j) { av[j] = ap4[j]; bv[j] = bp4[j]; }
        __syncthreads();
#pragma unroll
        for (int j = 0; j < 4; ++j) {
            *(uint4*)&As[sr][sk + 8 * j] = av[j];
            *(uint4*)&Bs[sr][sk + 8 * j] = bv[j];
        }
        __syncthreads();
#pragma unroll
        for (int kk = 0; kk < 2; ++kk) {
            bf16x8 a[4], b[4];
#pragma unroll
            for (int m = 0; m < 4; ++m)
                a[m] = *(const bf16x8*)&As[wm + m * 16 + fr][kk * 32 + fk8];
#pragma unroll
            for (int n = 0; n < 4; ++n)
                b[n] = *(const bf16x8*)&Bs[wn + n * 16 + fr][kk * 32 + fk8];
#pragma unroll
            for (int m = 0; m < 4; ++m)
#pragma unroll
                for (int n = 0; n < 4; ++n)
                    acc[m][n] = __builtin_amdgcn_mfma_f32_16x16x32_bf16(a[m], b[n], acc[m][n], 0, 0, 0);
        }
    }
#pragma unroll
    for (int m = 0; m < 4; ++m)
#pragma unroll
        for (int n = 0; n < 4; ++n)
#pragma unroll
            for (int i = 0; i < 4; ++i) {
                const size_t row = bm + wm + m * 16 + (lane >> 4) * 4 + i;
                const int col = (int)bn + wn + n * 16 + fr;
                float v = acc[m][n][i] + bias[col];
                if (RELU) v = fmaxf(v, 0.f);
                if (OUTBF16) ((short*)Cout)[row * (size_t)N + col] = f2bf(v);
                else         ((float*)Cout)[row * (size_t)N + col] = v;
            }
}

extern "C" void kernel_launch(void* const* d_in, const int* in_sizes, int n_in,
                              void* d_out, int out_size, void* d_ws, size_t ws_size,
                              hipStream_t stream)
{
    const float* x   = (const float*)d_in[0];
    const float* W1  = (const float*)d_in[1];
    const float* b1  = (const float*)d_in[2];
    const float* W2  = (const float*)d_in[3];
    const float* b2  = (const float*)d_in[4];
    const float* E   = (const float*)d_in[5];
    const float* Wd1 = (const float*)d_in[6];
    const float* bd1 = (const float*)d_in[7];
    const float* Wd2 = (const float*)d_in[8];
    const float* bd2 = (const float*)d_in[9];
    float* out = (float*)d_out;

    float* ws = (float*)d_ws;
    float*  h    = ws;                          // f32 [0, 33.5M); dead after GEMM2
    short*  a1b  = (short*)ws;                  // bf16 overlay on dead h
    short*  qb   = (short*)(ws + 16777216);
    float*  z    = ws + 33554432;               // 16,777,216 f32
    float*  q    = ws + 50331648;               // 16,777,216 f32
    float*  d2   = ws + 67108864;               //  8,388,608 f32; dead after argmin
    short*  Wd1t = (short*)(ws + 67108864);     // overlay on dead d2
    short*  Wd2t = (short*)(ws + 67108864 + 65536);
    float*  z2v  = ws + 75497472;               // 32,768
    float*  e2v  = ws + 75530240;               // 256
    double* partials = (double*)(ws + 75530496);// 1024 f64 = 2048 f32 slots
    float*  Et   = ws + 75532544;               // 512*256 = 131,072 f32

    dim3 blk(256);
    // encoder: f64-LDS injective swizzle + global prefetch, bit-exact chain
    gemm_f64<<<dim3(512, 8), blk, 0, stream>>>(x, W1, b1, nullptr, h, 1024, 512, 512, 1024);
    gemm_f64<<<dim3(512, 4), blk, 0, stream>>>(h, W2, b2, nullptr, z, 512, 256, 256, 512);
    // VQ (bit-exact round-5 semantics); E transposed exactly so d2 reuses the same kernel
    transpose_f32<<<dim3(512), blk, 0, stream>>>(E, Et);
    rowsq_np<<<dim3(1), blk, 0, stream>>>(E, e2v, 256);
    rowsq_np<<<dim3(128), blk, 0, stream>>>(z, z2v, 32768);
    gemm_f64<<<dim3(256, 4), blk, 0, stream>>>(z, Et, z2v, e2v, d2, 512, 256, 256, 512);
    argmin_gather<<<dim3(8192), blk, 0, stream>>>(d2, E, q, qb);
    // vq_loss = 1.25 * mean((q - z)^2)
    loss_partial<<<dim3(1024), blk, 0, stream>>>(z, q, partials, 4194304L);
    loss_final<<<dim3(1), blk, 0, stream>>>(partials, out + (size_t)out_size - 1);
    // decoder weights -> bf16 [N][K] (d2 dead)
    transpose_bf16<<<dim3(512), blk, 0, stream>>>(Wd1, Wd1t, 512, 8, 131072L);
    transpose_bf16<<<dim3(2048), blk, 0, stream>>>(Wd2, Wd2t, 1024, 9, 524288L);
    // decoder (bf16 MFMA; zq == q in forward)
    gemm_dec_bf16<true,  true ><<<dim3(512, 4), blk, 0, stream>>>(qb,  Wd1t, bd1, a1b, 512, 256);
    gemm_dec_bf16<false, false><<<dim3(512, 8), blk, 0, stream>>>(a1b, Wd2t, bd2, out, 1024, 512);
}